// Round 8
// baseline (33.502 us; speedup 1.0000x reference)
//
#include <hip/hip_runtime.h>
#include <math.h>

// Problem constants (fixed by setup_inputs)
#define BATCH 4
#define NPTS  2048
#define CHAN  32
#define CONVF 332.07156

#define ROWS 8            // rows per block
#define THREADS 256
#define NBLOCKS ((BATCH * NPTS / ROWS) * 2)   // 2048: (rowblk, jhalf)

// --- Kernel A: pack per-(b,n) j-side data + i-side embedding dot ----------
// pk[bn] = {x, y, z, q} , {Px, Py, Pz, aj}
// ai[bn] = dot(embs[bn], w[C:2C])
__global__ void pack_points(const float* __restrict__ X,
                            const float* __restrict__ embs,
                            const float* __restrict__ qs,
                            const float* __restrict__ Ps,
                            const float* __restrict__ sfw,
                            float4* __restrict__ pk,   // (B*N*2)
                            float* __restrict__ ai) {
    int idx = blockIdx.x * blockDim.x + threadIdx.x;
    if (idx >= BATCH * NPTS) return;
    int n = idx & (NPTS - 1);
    const float* e = embs + (size_t)idx * CHAN;
    float sj = 0.f, si = 0.f;
#pragma unroll
    for (int k = 0; k < CHAN; ++k) {
        float ev = e[k];
        sj = fmaf(ev, sfw[k], sj);
        si = fmaf(ev, sfw[CHAN + k], si);
    }
    float4 a, b;
    a.x = X[idx * 3 + 0];
    a.y = X[idx * 3 + 1];
    a.z = X[idx * 3 + 2];
    a.w = qs[n];
    b.x = Ps[n * 3 + 0];
    b.y = Ps[n * 3 + 1];
    b.z = Ps[n * 3 + 2];
    b.w = sj;                      // aj
    pk[idx * 2 + 0] = a;
    pk[idx * 2 + 1] = b;
    ai[idx] = si;
}

// --- Kernel B: double-buffered LDS mask pipeline (stage t+1 || compute t) -
__global__ __launch_bounds__(THREADS, 2) void pair_energy(
    const float4* __restrict__ pk,   // (B*N*2)
    const float* __restrict__ ai,    // (B*N)
    const float4* __restrict__ mask4,// (B*N*N/4)
    const float* __restrict__ sfw,   // (2C+1,)
    double* __restrict__ partials)   // (NBLOCKS,)
{
    const float wd = sfw[2 * CHAN];
    const int rowblk = blockIdx.x >> 1;
    const int jhalf  = blockIdx.x & 1;
    const int r0 = rowblk * ROWS;          // global row = b*N + i
    const int b  = r0 >> 11;
    const int jbase = b * NPTS;
    const int tid = threadIdx.x;
    const int wid = tid >> 6;
    const int jq = jhalf * THREADS + tid;   // j-quad index 0..511
    const int j0 = jq << 2;

    // double-buffered 1-row tiles: 2 x 256 float4 = 8 KB
    __shared__ float4 smask[2][256];

    // ---- prologue: stage row 0 (linear lane-order dest, m104 layout) ----
    {
        const float4* g = &mask4[(size_t)r0 * (NPTS / 4) + jq];
        __builtin_amdgcn_global_load_lds(
            (const __attribute__((address_space(1))) void*)g,
            (__attribute__((address_space(3))) void*)&smask[0][wid * 64],
            16, 0, 0);
    }

    // ---- j-side register loads (L2-resident) ----
    float4 ja[4], jb[4];
#pragma unroll
    for (int t = 0; t < 4; ++t) {
        ja[t] = pk[(jbase + j0 + t) * 2 + 0];
        jb[t] = pk[(jbase + j0 + t) * 2 + 1];
    }

    // ---- pipelined loop: stage row t+1, compute row t ----
    double acc = 0.0;
#pragma unroll
    for (int t = 0; t < ROWS; ++t) {
        const int cur = t & 1;
        __syncthreads();   // drains vmcnt: row t staged; prev reads done
        if (t + 1 < ROWS) {
            const float4* g = &mask4[(size_t)(r0 + t + 1) * (NPTS / 4) + jq];
            __builtin_amdgcn_global_load_lds(
                (const __attribute__((address_space(1))) void*)g,
                (__attribute__((address_space(3))) void*)&smask[cur ^ 1][wid * 64],
                16, 0, 0);
        }

        // i-side: block-uniform -> scalar loads / SGPRs
        float4 a = pk[(r0 + t) * 2 + 0];
        float4 p = pk[(r0 + t) * 2 + 1];
        float aw = ai[r0 + t];
        float cP = 1e-6f * (p.x + p.y + p.z);   // eps-dot, row-constant
        float4 mr = smask[cur][tid];            // ds_read_b128, conflict-free
        float es = 0.f;
#pragma unroll
        for (int u = 0; u < 4; ++u) {
            float dx = ja[u].x - a.x;
            float dy = ja[u].y - a.y;
            float dz = ja[u].z - a.z;
            float d2 = fmaf(dx, dx, fmaf(dy, dy, fmaf(dz, dz, 3e-6f)));
            float invD = __builtin_amdgcn_rsqf(d2);   // ~ 1/(D+1e-6), ~ 1/|V+eps|
            float OqP = fmaf(dx, p.x, fmaf(dy, p.y, fmaf(dz, p.z, cP)));
            float OPP = fmaf(p.x, jb[u].x, fmaf(p.y, jb[u].y, p.z * jb[u].z));
            float Q12 = a.w * ja[u].w;
            float sf  = fmaf(invD, wd, aw + jb[u].w);
            float invD2 = invD * invD;
            float invD4 = invD2 * invD2;
            float invD5 = invD4 * invD;
            float invD6 = invD4 * invD2;
            float E = fmaf(Q12 * invD, sf,
                      fmaf(OqP, invD5, OPP * invD6));
            float mv = (u == 0) ? mr.x : (u == 1) ? mr.y : (u == 2) ? mr.z : mr.w;
            es = fmaf(mv, E, es);
        }
        acc += (double)es;
    }

    // ---- wave shuffle reduce + 4-entry LDS combine ----
#pragma unroll
    for (int s = 32; s > 0; s >>= 1)
        acc += __shfl_xor(acc, s, 64);

    __shared__ double wsum[THREADS / 64];
    const int lane = tid & 63;
    if (lane == 0) wsum[wid] = acc;
    __syncthreads();
    if (tid == 0)
        partials[blockIdx.x] = wsum[0] + wsum[1] + wsum[2] + wsum[3];
}

// --- Kernel C: final reduction + scale + NaN guard ------------------------
__global__ void finalize(const double* __restrict__ partials, int n,
                         float* __restrict__ out) {
    __shared__ double sdata[256];
    double a = 0.0;
    for (int i = threadIdx.x; i < n; i += 256) a += partials[i];
    sdata[threadIdx.x] = a;
    __syncthreads();
#pragma unroll
    for (int s = 128; s > 0; s >>= 1) {
        if (threadIdx.x < s) sdata[threadIdx.x] += sdata[threadIdx.x + s];
        __syncthreads();
    }
    if (threadIdx.x == 0) {
        double tot = sdata[0] * (double)CONVF * 0.5;
        float f = (float)tot;
        out[0] = isnan(f) ? 1e-6f : f;
    }
}

extern "C" void kernel_launch(void* const* d_in, const int* in_sizes, int n_in,
                              void* d_out, int out_size, void* d_ws, size_t ws_size,
                              hipStream_t stream) {
    const float* X    = (const float*)d_in[0];
    const float* embs = (const float*)d_in[1];
    const float* qs   = (const float*)d_in[2];
    const float* Ps   = (const float*)d_in[3];
    const float* mask = (const float*)d_in[4];
    const float* sfw  = (const float*)d_in[5];
    float* out = (float*)d_out;

    // workspace: [ partials double[NBLOCKS] | pk float4[B*N*2] | ai float[B*N] ]
    double* partials = (double*)d_ws;
    float4* pk = (float4*)(partials + NBLOCKS);
    float*  ai = (float*)(pk + BATCH * NPTS * 2);

    pack_points<<<(BATCH * NPTS + 255) / 256, 256, 0, stream>>>(X, embs, qs, Ps, sfw, pk, ai);
    pair_energy<<<NBLOCKS, THREADS, 0, stream>>>(pk, ai, (const float4*)mask, sfw, partials);
    finalize<<<1, 256, 0, stream>>>(partials, NBLOCKS, out);
}

// Round 9
// 29.724 us; speedup vs baseline: 1.1271x; 1.1271x over previous
//
#include <hip/hip_runtime.h>
#include <math.h>

// Problem constants (fixed by setup_inputs)
#define BATCH 4
#define NPTS  2048
#define CHAN  32
#define CONVF 332.07156

#define ROWS 8
#define THREADS 256
#define NBLOCKS ((BATCH * NPTS / ROWS) * 2)   // 2048: (rowblk, jhalf)

// --- Kernel A: pack per-(b,n) j-side data + i-side embedding dot ----------
// pk[bn] = {x, y, z, q} , {Px, Py, Pz, aj}
// ai[bn] = dot(embs[bn], w[C:2C])
__global__ void pack_points(const float* __restrict__ X,
                            const float* __restrict__ embs,
                            const float* __restrict__ qs,
                            const float* __restrict__ Ps,
                            const float* __restrict__ sfw,
                            float4* __restrict__ pk,   // (B*N*2)
                            float* __restrict__ ai) {
    int idx = blockIdx.x * blockDim.x + threadIdx.x;
    if (idx >= BATCH * NPTS) return;
    int n = idx & (NPTS - 1);
    const float* e = embs + (size_t)idx * CHAN;
    float sj = 0.f, si = 0.f;
#pragma unroll
    for (int k = 0; k < CHAN; ++k) {
        float ev = e[k];
        sj = fmaf(ev, sfw[k], sj);
        si = fmaf(ev, sfw[CHAN + k], si);
    }
    float4 a, b;
    a.x = X[idx * 3 + 0];
    a.y = X[idx * 3 + 1];
    a.z = X[idx * 3 + 2];
    a.w = qs[n];
    b.x = Ps[n * 3 + 0];
    b.y = Ps[n * 3 + 1];
    b.z = Ps[n * 3 + 2];
    b.w = sj;                      // aj
    pk[idx * 2 + 0] = a;
    pk[idx * 2 + 1] = b;
    ai[idx] = si;
}

// --- Kernel B: 16-load burst held live via sched_barrier, counted vmcnt ---
__global__ __launch_bounds__(THREADS, 2) void pair_energy(
    const float4* __restrict__ pk,   // (B*N*2)
    const float* __restrict__ ai,    // (B*N)
    const float4* __restrict__ mask4,// (B*N*N/4)
    const float* __restrict__ sfw,   // (2C+1,)
    double* __restrict__ partials)   // (NBLOCKS,)
{
    const float wd = sfw[2 * CHAN];
    const int rowblk = blockIdx.x >> 1;
    const int jhalf  = blockIdx.x & 1;
    const int r0 = rowblk * ROWS;          // global row = b*N + i
    const int b  = r0 >> 11;
    const int jbase = b * NPTS;
    const int tid = threadIdx.x;
    const int jq = jhalf * THREADS + tid;   // j-quad index 0..511
    const int j0 = jq << 2;

    // ---- load section: 8 pk j-side loads, then 8 mask rows (consumption order)
    float4 ja[4], jb[4];
#pragma unroll
    for (int t = 0; t < 4; ++t) {
        ja[t] = pk[(jbase + j0 + t) * 2 + 0];
        jb[t] = pk[(jbase + j0 + t) * 2 + 1];
    }
    float4 m[ROWS];
#pragma unroll
    for (int r = 0; r < ROWS; ++r)
        m[r] = mask4[(size_t)(r0 + r) * (NPTS / 4) + jq];

    // Pin the boundary: no load may sink past here, no compute may hoist up.
    // Forces all 16 loads outstanding -> waitcnt pass emits counted vmcnt
    // per mask row (vmcnt(7-r)), pipelining latency under row compute.
    __builtin_amdgcn_sched_barrier(0);

    // ---- compute: 8 rows x 4 pairs ----
    double acc = 0.0;
#pragma unroll
    for (int r = 0; r < ROWS; ++r) {
        // i-side: block-uniform -> scalar loads / SGPRs (lgkmcnt, no vmcnt)
        float4 a = pk[(r0 + r) * 2 + 0];
        float4 p = pk[(r0 + r) * 2 + 1];
        float aw = ai[r0 + r];
        float cP = 1e-6f * (p.x + p.y + p.z);   // eps-dot, row-constant
        float es = 0.f;
#pragma unroll
        for (int t = 0; t < 4; ++t) {
            float dx = ja[t].x - a.x;
            float dy = ja[t].y - a.y;
            float dz = ja[t].z - a.z;
            float d2 = fmaf(dx, dx, fmaf(dy, dy, fmaf(dz, dz, 3e-6f)));
            float invD = __builtin_amdgcn_rsqf(d2);   // ~ 1/(D+1e-6), ~ 1/|V+eps|
            float OqP = fmaf(dx, p.x, fmaf(dy, p.y, fmaf(dz, p.z, cP)));
            float OPP = fmaf(p.x, jb[t].x, fmaf(p.y, jb[t].y, p.z * jb[t].z));
            float Q12 = a.w * ja[t].w;
            float sf  = fmaf(invD, wd, aw + jb[t].w);
            float invD2 = invD * invD;
            float invD4 = invD2 * invD2;
            float invD5 = invD4 * invD;
            float invD6 = invD4 * invD2;
            float E = fmaf(Q12 * invD, sf,
                      fmaf(OqP, invD5, OPP * invD6));
            float mv = (t == 0) ? m[r].x : (t == 1) ? m[r].y : (t == 2) ? m[r].z : m[r].w;
            es = fmaf(mv, E, es);
        }
        acc += (double)es;
    }

    // ---- wave shuffle reduce + 4-entry LDS combine ----
#pragma unroll
    for (int s = 32; s > 0; s >>= 1)
        acc += __shfl_xor(acc, s, 64);

    __shared__ double wsum[THREADS / 64];
    const int lane = tid & 63;
    const int wid  = tid >> 6;
    if (lane == 0) wsum[wid] = acc;
    __syncthreads();
    if (tid == 0)
        partials[blockIdx.x] = wsum[0] + wsum[1] + wsum[2] + wsum[3];
}

// --- Kernel C: final reduction + scale + NaN guard ------------------------
__global__ void finalize(const double* __restrict__ partials, int n,
                         float* __restrict__ out) {
    __shared__ double sdata[256];
    double a = 0.0;
    for (int i = threadIdx.x; i < n; i += 256) a += partials[i];
    sdata[threadIdx.x] = a;
    __syncthreads();
#pragma unroll
    for (int s = 128; s > 0; s >>= 1) {
        if (threadIdx.x < s) sdata[threadIdx.x] += sdata[threadIdx.x + s];
        __syncthreads();
    }
    if (threadIdx.x == 0) {
        double tot = sdata[0] * (double)CONVF * 0.5;
        float f = (float)tot;
        out[0] = isnan(f) ? 1e-6f : f;
    }
}

extern "C" void kernel_launch(void* const* d_in, const int* in_sizes, int n_in,
                              void* d_out, int out_size, void* d_ws, size_t ws_size,
                              hipStream_t stream) {
    const float* X    = (const float*)d_in[0];
    const float* embs = (const float*)d_in[1];
    const float* qs   = (const float*)d_in[2];
    const float* Ps   = (const float*)d_in[3];
    const float* mask = (const float*)d_in[4];
    const float* sfw  = (const float*)d_in[5];
    float* out = (float*)d_out;

    // workspace: [ partials double[NBLOCKS] | pk float4[B*N*2] | ai float[B*N] ]
    double* partials = (double*)d_ws;
    float4* pk = (float4*)(partials + NBLOCKS);
    float*  ai = (float*)(pk + BATCH * NPTS * 2);

    pack_points<<<(BATCH * NPTS + 255) / 256, 256, 0, stream>>>(X, embs, qs, Ps, sfw, pk, ai);
    pair_energy<<<NBLOCKS, THREADS, 0, stream>>>(pk, ai, (const float4*)mask, sfw, partials);
    finalize<<<1, 256, 0, stream>>>(partials, NBLOCKS, out);
}

// Round 10
// 29.229 us; speedup vs baseline: 1.1462x; 1.0169x over previous
//
#include <hip/hip_runtime.h>
#include <math.h>

// Problem constants (fixed by setup_inputs)
#define BATCH 4
#define NPTS  2048
#define CHAN  32
#define CONVF 332.07156

#define ROWS 8
#define THREADS 256
#define NBLOCKS ((BATCH * NPTS / ROWS) * 2)   // 2048: (rowblk, jhalf)

typedef float f4v __attribute__((ext_vector_type(4)));

// --- Kernel A: pack per-(b,n) j-side data + i-side embedding dot ----------
// pk[bn] = {x, y, z, q} , {Px, Py, Pz, aj}
// ai[bn] = dot(embs[bn], w[C:2C])
__global__ void pack_points(const float* __restrict__ X,
                            const float* __restrict__ embs,
                            const float* __restrict__ qs,
                            const float* __restrict__ Ps,
                            const float* __restrict__ sfw,
                            float4* __restrict__ pk,   // (B*N*2)
                            float* __restrict__ ai) {
    int idx = blockIdx.x * blockDim.x + threadIdx.x;
    if (idx >= BATCH * NPTS) return;
    int n = idx & (NPTS - 1);
    const float* e = embs + (size_t)idx * CHAN;
    float sj = 0.f, si = 0.f;
#pragma unroll
    for (int k = 0; k < CHAN; ++k) {
        float ev = e[k];
        sj = fmaf(ev, sfw[k], sj);
        si = fmaf(ev, sfw[CHAN + k], si);
    }
    float4 a, b;
    a.x = X[idx * 3 + 0];
    a.y = X[idx * 3 + 1];
    a.z = X[idx * 3 + 2];
    a.w = qs[n];
    b.x = Ps[n * 3 + 0];
    b.y = Ps[n * 3 + 1];
    b.z = Ps[n * 3 + 2];
    b.w = sj;                      // aj
    pk[idx * 2 + 0] = a;
    pk[idx * 2 + 1] = b;
    ai[idx] = si;
}

// --- Kernel B: 16-load burst, mask loads NONTEMPORAL (stream past L1) -----
__global__ __launch_bounds__(THREADS, 2) void pair_energy(
    const float4* __restrict__ pk,   // (B*N*2)
    const float* __restrict__ ai,    // (B*N)
    const float4* __restrict__ mask4,// (B*N*N/4)
    const float* __restrict__ sfw,   // (2C+1,)
    double* __restrict__ partials)   // (NBLOCKS,)
{
    const float wd = sfw[2 * CHAN];
    const int rowblk = blockIdx.x >> 1;
    const int jhalf  = blockIdx.x & 1;
    const int r0 = rowblk * ROWS;          // global row = b*N + i
    const int b  = r0 >> 11;
    const int jbase = b * NPTS;
    const int tid = threadIdx.x;
    const int jq = jhalf * THREADS + tid;   // j-quad index 0..511
    const int j0 = jq << 2;

    // ---- load section: 8 pk j-side loads (cached), 8 mask rows (nt) ----
    float4 ja[4], jb[4];
#pragma unroll
    for (int t = 0; t < 4; ++t) {
        ja[t] = pk[(jbase + j0 + t) * 2 + 0];
        jb[t] = pk[(jbase + j0 + t) * 2 + 1];
    }
    f4v m[ROWS];
#pragma unroll
    for (int r = 0; r < ROWS; ++r) {
        const f4v* g = (const f4v*)&mask4[(size_t)(r0 + r) * (NPTS / 4) + jq];
        m[r] = __builtin_nontemporal_load(g);   // global_load_dwordx4 ... nt
    }

    // Pin the boundary: all 16 loads outstanding before compute.
    __builtin_amdgcn_sched_barrier(0);

    // ---- compute: 8 rows x 4 pairs ----
    double acc = 0.0;
#pragma unroll
    for (int r = 0; r < ROWS; ++r) {
        // i-side: block-uniform -> scalar loads / SGPRs
        float4 a = pk[(r0 + r) * 2 + 0];
        float4 p = pk[(r0 + r) * 2 + 1];
        float aw = ai[r0 + r];
        float cP = 1e-6f * (p.x + p.y + p.z);   // eps-dot, row-constant
        float es = 0.f;
#pragma unroll
        for (int t = 0; t < 4; ++t) {
            float dx = ja[t].x - a.x;
            float dy = ja[t].y - a.y;
            float dz = ja[t].z - a.z;
            float d2 = fmaf(dx, dx, fmaf(dy, dy, fmaf(dz, dz, 3e-6f)));
            float invD = __builtin_amdgcn_rsqf(d2);   // ~ 1/(D+1e-6), ~ 1/|V+eps|
            float OqP = fmaf(dx, p.x, fmaf(dy, p.y, fmaf(dz, p.z, cP)));
            float OPP = fmaf(p.x, jb[t].x, fmaf(p.y, jb[t].y, p.z * jb[t].z));
            float Q12 = a.w * ja[t].w;
            float sf  = fmaf(invD, wd, aw + jb[t].w);
            float invD2 = invD * invD;
            float invD4 = invD2 * invD2;
            float invD5 = invD4 * invD;
            float invD6 = invD4 * invD2;
            float E = fmaf(Q12 * invD, sf,
                      fmaf(OqP, invD5, OPP * invD6));
            float mv = (t == 0) ? m[r].x : (t == 1) ? m[r].y : (t == 2) ? m[r].z : m[r].w;
            es = fmaf(mv, E, es);
        }
        acc += (double)es;
    }

    // ---- wave shuffle reduce + 4-entry LDS combine ----
#pragma unroll
    for (int s = 32; s > 0; s >>= 1)
        acc += __shfl_xor(acc, s, 64);

    __shared__ double wsum[THREADS / 64];
    const int lane = tid & 63;
    const int wid  = tid >> 6;
    if (lane == 0) wsum[wid] = acc;
    __syncthreads();
    if (tid == 0)
        partials[blockIdx.x] = wsum[0] + wsum[1] + wsum[2] + wsum[3];
}

// --- Kernel C: final reduction + scale + NaN guard ------------------------
__global__ void finalize(const double* __restrict__ partials, int n,
                         float* __restrict__ out) {
    __shared__ double sdata[256];
    double a = 0.0;
    for (int i = threadIdx.x; i < n; i += 256) a += partials[i];
    sdata[threadIdx.x] = a;
    __syncthreads();
#pragma unroll
    for (int s = 128; s > 0; s >>= 1) {
        if (threadIdx.x < s) sdata[threadIdx.x] += sdata[threadIdx.x + s];
        __syncthreads();
    }
    if (threadIdx.x == 0) {
        double tot = sdata[0] * (double)CONVF * 0.5;
        float f = (float)tot;
        out[0] = isnan(f) ? 1e-6f : f;
    }
}

extern "C" void kernel_launch(void* const* d_in, const int* in_sizes, int n_in,
                              void* d_out, int out_size, void* d_ws, size_t ws_size,
                              hipStream_t stream) {
    const float* X    = (const float*)d_in[0];
    const float* embs = (const float*)d_in[1];
    const float* qs   = (const float*)d_in[2];
    const float* Ps   = (const float*)d_in[3];
    const float* mask = (const float*)d_in[4];
    const float* sfw  = (const float*)d_in[5];
    float* out = (float*)d_out;

    // workspace: [ partials double[NBLOCKS] | pk float4[B*N*2] | ai float[B*N] ]
    double* partials = (double*)d_ws;
    float4* pk = (float4*)(partials + NBLOCKS);
    float*  ai = (float*)(pk + BATCH * NPTS * 2);

    pack_points<<<(BATCH * NPTS + 255) / 256, 256, 0, stream>>>(X, embs, qs, Ps, sfw, pk, ai);
    pair_energy<<<NBLOCKS, THREADS, 0, stream>>>(pk, ai, (const float4*)mask, sfw, partials);
    finalize<<<1, 256, 0, stream>>>(partials, NBLOCKS, out);
}

// Round 11
// 27.751 us; speedup vs baseline: 1.2072x; 1.0533x over previous
//
#include <hip/hip_runtime.h>
#include <math.h>

// Problem constants (fixed by setup_inputs)
#define BATCH 4
#define NPTS  2048
#define CHAN  32
#define CONVF 332.07156

#define ROWS 8
#define THREADS 256
#define NBLOCKS ((BATCH * NPTS / ROWS) * 2)   // 2048: (rowblk, jhalf)
#define NQUADS (BATCH * NPTS / 4)             // 2048 quads, plane stride
#define QPB (NPTS / 4)                        // 512 quads per batch row

typedef float f4v __attribute__((ext_vector_type(4)));

// --- Kernel A: pack i-side structs + quad-transposed j-side planes --------
// pk[bn]   = {x,y,z,q},{Px,Py,Pz,aj}   (i-side, uniform reads)
// pkT[s][quad] = plane s of the 4 points in the quad (j-side, coalesced)
// ai[bn]   = dot(embs[bn], w[C:2C])
__global__ void pack_points(const float* __restrict__ X,
                            const float* __restrict__ embs,
                            const float* __restrict__ qs,
                            const float* __restrict__ Ps,
                            const float* __restrict__ sfw,
                            float4* __restrict__ pk,   // (B*N*2)
                            float* __restrict__ ai,    // (B*N)
                            float* __restrict__ pkT) { // (8*NQUADS*4)
    int idx = blockIdx.x * blockDim.x + threadIdx.x;
    if (idx >= BATCH * NPTS) return;
    int n = idx & (NPTS - 1);
    const float* e = embs + (size_t)idx * CHAN;
    float sj = 0.f, si = 0.f;
#pragma unroll
    for (int k = 0; k < CHAN; ++k) {
        float ev = e[k];
        sj = fmaf(ev, sfw[k], sj);
        si = fmaf(ev, sfw[CHAN + k], si);
    }
    float xv = X[idx * 3 + 0], yv = X[idx * 3 + 1], zv = X[idx * 3 + 2];
    float qv = qs[n];
    float Px = Ps[n * 3 + 0], Py = Ps[n * 3 + 1], Pz = Ps[n * 3 + 2];

    float4 a, bb;
    a.x = xv; a.y = yv; a.z = zv; a.w = qv;
    bb.x = Px; bb.y = Py; bb.z = Pz; bb.w = sj;
    pk[idx * 2 + 0] = a;
    pk[idx * 2 + 1] = bb;
    ai[idx] = si;

    // quad-transposed planes: pkT[(s*NQUADS + q)*4 + t]
    int q = idx >> 2, t = idx & 3;
    pkT[(0 * NQUADS + q) * 4 + t] = xv;
    pkT[(1 * NQUADS + q) * 4 + t] = yv;
    pkT[(2 * NQUADS + q) * 4 + t] = zv;
    pkT[(3 * NQUADS + q) * 4 + t] = qv;
    pkT[(4 * NQUADS + q) * 4 + t] = Px;
    pkT[(5 * NQUADS + q) * 4 + t] = Py;
    pkT[(6 * NQUADS + q) * 4 + t] = Pz;
    pkT[(7 * NQUADS + q) * 4 + t] = sj;
}

// --- Kernel B: all loads coalesced 16B/lane; 8 rows x 4 j per thread ------
__global__ __launch_bounds__(THREADS, 2) void pair_energy(
    const float4* __restrict__ pk,   // (B*N*2)  i-side
    const float* __restrict__ ai,    // (B*N)
    const f4v* __restrict__ pkT4,    // (8*NQUADS) j-side planes
    const f4v* __restrict__ mask4,   // (B*N*N/4)
    const float* __restrict__ sfw,   // (2C+1,)
    double* __restrict__ partials)   // (NBLOCKS,)
{
    const float wd = sfw[2 * CHAN];
    const int rowblk = blockIdx.x >> 1;
    const int jhalf  = blockIdx.x & 1;
    const int r0 = rowblk * ROWS;          // global row = b*N + i
    const int b  = r0 >> 11;
    const int tid = threadIdx.x;
    const int jq = jhalf * THREADS + tid;  // quad within row, 0..511
    const int qidx = b * QPB + jq;         // global quad index

    // ---- j-side planes: 8 perfectly-coalesced loads ----
    f4v vx  = pkT4[0 * NQUADS + qidx];
    f4v vy  = pkT4[1 * NQUADS + qidx];
    f4v vz  = pkT4[2 * NQUADS + qidx];
    f4v vq  = pkT4[3 * NQUADS + qidx];
    f4v vpx = pkT4[4 * NQUADS + qidx];
    f4v vpy = pkT4[5 * NQUADS + qidx];
    f4v vpz = pkT4[6 * NQUADS + qidx];
    f4v vaj = pkT4[7 * NQUADS + qidx];

    // ---- mask rows: 8 coalesced nontemporal loads ----
    f4v m[ROWS];
#pragma unroll
    for (int r = 0; r < ROWS; ++r)
        m[r] = __builtin_nontemporal_load(&mask4[(size_t)(r0 + r) * QPB + jq]);

    // Pin: all 16 loads outstanding before compute (counted vmcnt per row).
    __builtin_amdgcn_sched_barrier(0);

    // ---- compute: 8 rows x 4 pairs ----
    double acc = 0.0;
#pragma unroll
    for (int r = 0; r < ROWS; ++r) {
        // i-side: block-uniform
        float4 a = pk[(r0 + r) * 2 + 0];
        float4 p = pk[(r0 + r) * 2 + 1];
        float aw = ai[r0 + r];
        float cP = 1e-6f * (p.x + p.y + p.z);   // eps-dot, row-constant
        float es = 0.f;
#pragma unroll
        for (int t = 0; t < 4; ++t) {
            float dx = vx[t] - a.x;
            float dy = vy[t] - a.y;
            float dz = vz[t] - a.z;
            float d2 = fmaf(dx, dx, fmaf(dy, dy, fmaf(dz, dz, 3e-6f)));
            float invD = __builtin_amdgcn_rsqf(d2);   // ~ 1/(D+1e-6), ~ 1/|V+eps|
            float OqP = fmaf(dx, p.x, fmaf(dy, p.y, fmaf(dz, p.z, cP)));
            float OPP = fmaf(p.x, vpx[t], fmaf(p.y, vpy[t], p.z * vpz[t]));
            float Q12 = a.w * vq[t];
            float sf  = fmaf(invD, wd, aw + vaj[t]);
            float invD2 = invD * invD;
            float invD4 = invD2 * invD2;
            float invD5 = invD4 * invD;
            float invD6 = invD4 * invD2;
            float E = fmaf(Q12 * invD, sf,
                      fmaf(OqP, invD5, OPP * invD6));
            es = fmaf(m[r][t], E, es);
        }
        acc += (double)es;
    }

    // ---- wave shuffle reduce + 4-entry LDS combine ----
#pragma unroll
    for (int s = 32; s > 0; s >>= 1)
        acc += __shfl_xor(acc, s, 64);

    __shared__ double wsum[THREADS / 64];
    const int lane = tid & 63;
    const int wid  = tid >> 6;
    if (lane == 0) wsum[wid] = acc;
    __syncthreads();
    if (tid == 0)
        partials[blockIdx.x] = wsum[0] + wsum[1] + wsum[2] + wsum[3];
}

// --- Kernel C: final reduction + scale + NaN guard ------------------------
__global__ void finalize(const double* __restrict__ partials, int n,
                         float* __restrict__ out) {
    __shared__ double sdata[256];
    double a = 0.0;
    for (int i = threadIdx.x; i < n; i += 256) a += partials[i];
    sdata[threadIdx.x] = a;
    __syncthreads();
#pragma unroll
    for (int s = 128; s > 0; s >>= 1) {
        if (threadIdx.x < s) sdata[threadIdx.x] += sdata[threadIdx.x + s];
        __syncthreads();
    }
    if (threadIdx.x == 0) {
        double tot = sdata[0] * (double)CONVF * 0.5;
        float f = (float)tot;
        out[0] = isnan(f) ? 1e-6f : f;
    }
}

extern "C" void kernel_launch(void* const* d_in, const int* in_sizes, int n_in,
                              void* d_out, int out_size, void* d_ws, size_t ws_size,
                              hipStream_t stream) {
    const float* X    = (const float*)d_in[0];
    const float* embs = (const float*)d_in[1];
    const float* qs   = (const float*)d_in[2];
    const float* Ps   = (const float*)d_in[3];
    const float* mask = (const float*)d_in[4];
    const float* sfw  = (const float*)d_in[5];
    float* out = (float*)d_out;

    // workspace: [ partials double[NBLOCKS] | pk float4[B*N*2] | ai float[B*N]
    //            | pkT float[8*NQUADS*4] ]
    double* partials = (double*)d_ws;
    float4* pk  = (float4*)(partials + NBLOCKS);
    float*  ai  = (float*)(pk + BATCH * NPTS * 2);
    float*  pkT = ai + BATCH * NPTS;

    pack_points<<<(BATCH * NPTS + 255) / 256, 256, 0, stream>>>(X, embs, qs, Ps, sfw,
                                                                pk, ai, pkT);
    pair_energy<<<NBLOCKS, THREADS, 0, stream>>>(pk, ai, (const f4v*)pkT,
                                                 (const f4v*)mask, sfw, partials);
    finalize<<<1, 256, 0, stream>>>(partials, NBLOCKS, out);
}